// Round 9
// baseline (236.198 us; speedup 1.0000x reference)
//
#include <hip/hip_runtime.h>
#include <hip/hip_bf16.h>

// Fused causal MHA. B=2, S=2048, E=1024, H=16, D=64. fp32 in/out.
// R18 (resubmitted verbatim — prior run died at container level, no signal):
// gemm_qkv re-tiled 128x128 -> 128x64 (acc 4x2), dbuf LDS 48KB ->
// 3 blocks/CU, grid 1536 = 2 exact rounds (was 768 @2/CU = 1.5 rounds).
// Theory: R16/R17 occupancy stuck at 14% (~4.6 awake waves/CU) in both
// 32KB and 64KB configs -> waves sleep at the syncthreads vmcnt(0) drain;
// more independent full-dbuf barrier domains per CU = more awake waves.
// R17's 1-barrier dbuf sync pattern is kept verbatim (parameter change
// only). If occupancy rises but dur doesn't -> drain is structural ->
// R19 goes counted-vmcnt/raw-barrier.
// R13 lesson: LDS staging IS the prefetch pipeline. R14: setprio null.
// R16: v_exp_f32 + split S^T live ranges verified good.

typedef __bf16 bf16;
typedef bf16 bf16x2 __attribute__((ext_vector_type(2)));
typedef bf16 bf16x4 __attribute__((ext_vector_type(4)));
typedef bf16 bf16x8 __attribute__((ext_vector_type(8)));
typedef float f32x4 __attribute__((ext_vector_type(4)));
typedef float f32x16 __attribute__((ext_vector_type(16)));
typedef unsigned int u32x4 __attribute__((ext_vector_type(4)));

constexpr int BSZ = 2, SEQ = 2048, EMBED = 1024, HEADS = 16, HDIM = 64;
constexpr int MTOT = BSZ * SEQ;       // 4096
constexpr int KDIM = EMBED;           // 1024
constexpr float QSCALE = 0.125f * 1.4426950408889634f;  // 1/sqrt(64) * log2(e)

constexpr size_t XSZ = (size_t)MTOT * EMBED;   // 4M elems (1<<22)
constexpr size_t WSZ = (size_t)EMBED * EMBED;  // 1M elems (1<<20)

// async global->LDS, 16B/lane; lds dest wave-uniform base + lane*16
__device__ inline void load_lds16(const bf16* g, bf16* l) {
    __builtin_amdgcn_global_load_lds(
        (const __attribute__((address_space(1))) unsigned int*)g,
        (__attribute__((address_space(3))) unsigned int*)l, 16, 0, 0);
}

// bare v_exp_f32 (2^x); no libm special-case guards. -inf -> 0 in HW.
__device__ inline float fast_exp2(float x) {
    float r;
    asm("v_exp_f32 %0, %1" : "=v"(r) : "v"(x));
    return r;
}

// ---------------------------------------------------------------------------
// fp32 -> bf16 conversion: 3 X tensors (4M each) + 4 W tensors (1M each).
// ---------------------------------------------------------------------------
__global__ __launch_bounds__(256) void cvt_bf16(
    const float* __restrict__ x0, const float* __restrict__ x1, const float* __restrict__ x2,
    const float* __restrict__ w0, const float* __restrict__ w1,
    const float* __restrict__ w2, const float* __restrict__ w3,
    bf16* __restrict__ dst) {
    const size_t i = ((size_t)blockIdx.x * blockDim.x + threadIdx.x) * 8;
    const float* src;
    size_t off;
    if (i < 3 * XSZ) {
        const int s = (int)(i >> 22);
        src = s == 0 ? x0 : (s == 1 ? x1 : x2);
        off = i & (XSZ - 1);
    } else {
        const size_t j = i - 3 * XSZ;
        const int s = (int)(j >> 20);
        src = s == 0 ? w0 : (s == 1 ? w1 : (s == 2 ? w2 : w3));
        off = j & (WSZ - 1);
    }
    float4 a = *(const float4*)(src + off);
    float4 b = *(const float4*)(src + off + 4);
    bf16x8 v = {(bf16)a.x, (bf16)a.y, (bf16)a.z, (bf16)a.w,
                (bf16)b.x, (bf16)b.y, (bf16)b.z, (bf16)b.w};
    *(bf16x8*)(dst + i) = v;
}

// ---------------------------------------------------------------------------
// QKV projection, R18 geometry: 128(M) x 64(N) tiles, acc 4x2 per wave
// (wm=(w&1)*64, wn=(w>>1)*32 — gemm_out's verified layout). Double-buffered
// staging, 48KB LDS -> 3 blocks/CU; grid (32,16,3)=1536 = 2 exact rounds.
// z=0: Q scaled -> [B,H,S,D]; z=1: K -> [B,H,S,D]; z=2: V -> [B,H,D,S].
// ---------------------------------------------------------------------------
__global__ __launch_bounds__(256) void gemm_qkv(
    const bf16* __restrict__ Xq, const bf16* __restrict__ Xk, const bf16* __restrict__ Xv,
    const bf16* __restrict__ Wq, const bf16* __restrict__ Wk, const bf16* __restrict__ Wv,
    const float* __restrict__ bq, const float* __restrict__ bk, const float* __restrict__ bv,
    bf16* __restrict__ Qp, bf16* __restrict__ Kp, bf16* __restrict__ Vtp) {
    __shared__ bf16 As[256][64];   // 2 x 128 rows (double buffer)
    __shared__ bf16 Bs[128][64];   // 2 x 64 rows (double buffer)

    const int z = blockIdx.z;
    const bf16* A     = z == 0 ? Xq : (z == 1 ? Xk : Xv);
    const bf16* W     = z == 0 ? Wq : (z == 1 ? Wk : Wv);
    const float* bias = z == 0 ? bq : (z == 1 ? bk : bv);
    const float scale = z == 0 ? QSCALE : 1.0f;

    const int tid = threadIdx.x;
    const int wave = tid >> 6, lane = tid & 63;
    const int quad = lane >> 4, l16 = lane & 15;
    const int wm = (wave & 1) * 64, wn = (wave >> 1) * 32;
    const int lrow = lane >> 3, lcol = (lane & 7) * 8;
    const int rowA0 = blockIdx.x * 128;   // M rows
    const int rowB0 = blockIdx.y * 64;    // N features (one head col-block)

    auto stage = [&](int buf, int k0) {
#pragma unroll
        for (int i = 0; i < 4; ++i) {
            const int r0 = (wave * 4 + i) * 8;
            const int row = r0 + lrow;
            const int gcol = (lcol - 8 * row) & 63;
            load_lds16(&A[(size_t)(rowA0 + row) * KDIM + k0 + gcol], &As[buf * 128 + r0][0]);
        }
#pragma unroll
        for (int i = 0; i < 2; ++i) {
            const int r0 = (wave * 2 + i) * 8;
            const int row = r0 + lrow;
            const int gcol = (lcol - 8 * row) & 63;
            load_lds16(&W[(size_t)(rowB0 + row) * KDIM + k0 + gcol], &Bs[buf * 64 + r0][0]);
        }
    };

    f32x4 acc[4][2] = {};
    stage(0, 0);
    int cur = 0;
#pragma unroll 1
    for (int k0 = 0; k0 < KDIM; k0 += 64) {
        __syncthreads();               // cur's DMA landed; prior reads of cur done
        if (k0 + 64 < KDIM) stage(cur ^ 1, k0 + 64);
        for (int ks = 0; ks < 64; ks += 32) {
            bf16x8 af[4], bfr[2];
            for (int mt = 0; mt < 4; ++mt) {
                const int row = wm + mt * 16 + l16;
                af[mt] = *(const bf16x8*)&As[cur * 128 + row][(ks + quad * 8 + 8 * row) & 63];
            }
            for (int nt = 0; nt < 2; ++nt) {
                const int row = wn + nt * 16 + l16;
                bfr[nt] = *(const bf16x8*)&Bs[cur * 64 + row][(ks + quad * 8 + 8 * row) & 63];
            }
            for (int mt = 0; mt < 4; ++mt)
                for (int nt = 0; nt < 2; ++nt)
                    acc[mt][nt] = (z < 2)
                        ? __builtin_amdgcn_mfma_f32_16x16x32_bf16(bfr[nt], af[mt], acc[mt][nt], 0, 0, 0)
                        : __builtin_amdgcn_mfma_f32_16x16x32_bf16(af[mt], bfr[nt], acc[mt][nt], 0, 0, 0);
        }
        cur ^= 1;
    }

    if (z < 2) {
        bf16* dst = z == 0 ? Qp : Kp;
        for (int mt = 0; mt < 4; ++mt) {
            const int xrow = rowA0 + wm + mt * 16 + l16;
            const int b = xrow >> 11, s = xrow & (SEQ - 1);
            for (int nt = 0; nt < 2; ++nt) {
                const int f0 = rowB0 + wn + nt * 16 + quad * 4;
                const float4 bb = *(const float4*)&bias[f0];
                const int h = f0 >> 6, d0 = f0 & (HDIM - 1);
                f32x4 a = acc[mt][nt];
                bf16x4 pk = {(bf16)((a[0] + bb.x) * scale), (bf16)((a[1] + bb.y) * scale),
                             (bf16)((a[2] + bb.z) * scale), (bf16)((a[3] + bb.w) * scale)};
                *(bf16x4*)&dst[(((size_t)(b * HEADS + h)) * SEQ + s) * HDIM + d0] = pk;
            }
        }
    } else {
        for (int nt = 0; nt < 2; ++nt) {
            const int f = rowB0 + wn + nt * 16 + l16;
            const float bb = bias[f];
            const int h = f >> 6, d = f & (HDIM - 1);
            for (int mt = 0; mt < 4; ++mt) {
                const int xrow0 = rowA0 + wm + mt * 16 + quad * 4;
                const int b = xrow0 >> 11, s0 = xrow0 & (SEQ - 1);
                f32x4 a = acc[mt][nt];
                bf16x4 pk = {(bf16)(a[0] + bb), (bf16)(a[1] + bb),
                             (bf16)(a[2] + bb), (bf16)(a[3] + bb)};
                *(bf16x4*)&Vtp[(((size_t)(b * HEADS + h)) * HDIM + d) * SEQ + s0] = pk;
            }
        }
    }
}

// ---------------------------------------------------------------------------
// Output projection: 128x64 tiles -> grid (32,16) = 512 blocks.
// R17: 2-phase dbuf staging (48KB LDS -> 3/CU; all blocks resident).
// ---------------------------------------------------------------------------
__global__ __launch_bounds__(256) void gemm_out(const bf16* __restrict__ A,
                                                const bf16* __restrict__ W,
                                                const float* __restrict__ bias,
                                                float* __restrict__ C) {
    __shared__ bf16 As[256][64];   // 2 x 128 rows
    __shared__ bf16 Bs[128][64];   // 2 x 64 rows

    const int tid = threadIdx.x;
    const int wave = tid >> 6, lane = tid & 63;
    const int quad = lane >> 4, l16 = lane & 15;
    const int wm = (wave & 1) * 64, wn = (wave >> 1) * 32;
    const int lrow = lane >> 3, lcol = (lane & 7) * 8;
    const int rowA0 = blockIdx.x * 128;   // M rows
    const int rowB0 = blockIdx.y * 64;    // N features

    auto stage = [&](int buf, int k0) {
#pragma unroll
        for (int i = 0; i < 4; ++i) {
            const int r0 = (wave * 4 + i) * 8;
            const int row = r0 + lrow;
            const int gcol = (lcol - 8 * row) & 63;
            load_lds16(&A[(size_t)(rowA0 + row) * KDIM + k0 + gcol], &As[buf * 128 + r0][0]);
        }
#pragma unroll
        for (int i = 0; i < 2; ++i) {
            const int r0 = (wave * 2 + i) * 8;
            const int row = r0 + lrow;
            const int gcol = (lcol - 8 * row) & 63;
            load_lds16(&W[(size_t)(rowB0 + row) * KDIM + k0 + gcol], &Bs[buf * 64 + r0][0]);
        }
    };

    f32x4 acc[4][2] = {};
    stage(0, 0);
    int cur = 0;
#pragma unroll 1
    for (int k0 = 0; k0 < KDIM; k0 += 64) {
        __syncthreads();               // cur's DMA landed; prior reads done
        if (k0 + 64 < KDIM) stage(cur ^ 1, k0 + 64);
        for (int ks = 0; ks < 64; ks += 32) {
            bf16x8 af[4], bfr[2];
            for (int mt = 0; mt < 4; ++mt) {
                const int row = wm + mt * 16 + l16;
                af[mt] = *(const bf16x8*)&As[cur * 128 + row][(ks + quad * 8 + 8 * row) & 63];
            }
            for (int nt = 0; nt < 2; ++nt) {
                const int row = wn + nt * 16 + l16;
                bfr[nt] = *(const bf16x8*)&Bs[cur * 64 + row][(ks + quad * 8 + 8 * row) & 63];
            }
            for (int mt = 0; mt < 4; ++mt)
                for (int nt = 0; nt < 2; ++nt)
                    acc[mt][nt] = __builtin_amdgcn_mfma_f32_16x16x32_bf16(
                        bfr[nt], af[mt], acc[mt][nt], 0, 0, 0);   // SWAP orientation
        }
        cur ^= 1;
    }

    for (int mt = 0; mt < 4; ++mt) {
        const int row = rowA0 + wm + mt * 16 + l16;
        for (int nt = 0; nt < 2; ++nt) {
            const int f0 = rowB0 + wn + nt * 16 + quad * 4;
            const float4 bb = *(const float4*)&bias[f0];
            f32x4 a = acc[mt][nt];
            float4 v = {a[0] + bb.x, a[1] + bb.y, a[2] + bb.z, a[3] + bb.w};
            *(float4*)&C[(size_t)row * EMBED + f0] = v;
        }
    }
}

// ---------------------------------------------------------------------------
// Flash attention, causal. R16 (unchanged): 32x32x16 MFMA, in-register P,
// 256 blocks x 4 waves; block owns q-tiles {15-p, p} (128 rows each).
// Per 128-key iter per wave, two 64-key half-passes:
//   QK^T (8 MFMA) -> mask -> exp2 (v_exp_f32) -> pack+permlane -> PV (12
//   MFMA incl. ones-denominator); st[2] live instead of st[4].
// K/V double-buffered DMA staging (L2-resident; 4 heads per XCD). LDS 64KB.
// ---------------------------------------------------------------------------
__global__ __launch_bounds__(256, 1) void attn_flash(const bf16* __restrict__ Q,
                                                     const bf16* __restrict__ K,
                                                     const bf16* __restrict__ Vt,
                                                     bf16* __restrict__ O) {
    const int l = blockIdx.x;                    // 0..255
    const int a = l & 7, s = l >> 3;             // XCD, slot 0..31
    const int bh = 4 * a + (s >> 3);             // 4 heads per XCD
    const int p = s & 7;                         // 0..7
    const int wave = threadIdx.x >> 6, lane = threadIdx.x & 63;
    const int r32 = lane & 31, half = lane >> 5;

    const bf16* Qh = Q + (size_t)bh * SEQ * HDIM;
    const bf16* Kh = K + (size_t)bh * SEQ * HDIM;
    const bf16* Vh = Vt + (size_t)bh * HDIM * SEQ;

    __shared__ bf16 Ks[2][128][64];  // [buf][key][d], col rotated by 8*key mod 64
    __shared__ bf16 Vs[2][64][128];  // [buf][d][key], col rotated by 8*d mod 128

    const int b = bh >> 4, h = bh & 15;

    // stage one 128-key tile (K: 128x64, V: 64x128), 4 DMA passes each
    auto stage = [&](int buf, int k0) {
#pragma unroll
        for (int cc = 0; cc < 4; ++cc) {
            const int krow = cc * 32 + wave * 8 + (lane >> 3);        // 0..127
            const int kg = (((lane & 7) * 8) - 8 * krow) & 63;
            load_lds16(&Kh[(size_t)(k0 + krow) * HDIM + kg], &Ks[buf][cc * 32 + wave * 8][0]);
            const int vrow = cc * 16 + wave * 4 + (lane >> 4);        // 0..63
            const int vg = (((lane & 15) * 8) - 8 * vrow) & 127;
            load_lds16(&Vh[(size_t)vrow * SEQ + k0 + vg], &Vs[buf][cc * 16 + wave * 4][0]);
        }
    };

    bf16x8 ones;
#pragma unroll
    for (int i = 0; i < 8; ++i) ones[i] = (bf16)1.0f;

#pragma unroll 1
    for (int phase = 0; phase < 2; ++phase) {
        const int qt = phase == 0 ? (15 - p) : p;    // 128-row q-tile index
        const int qw = qt * 128 + wave * 32;         // this wave's 32 q-rows
        const int nk = qt + 1;                       // 128-key iterations

        // Q^T B-frags: lane supplies Q[qw+r32][kc*16 + half*8 + e]
        bf16x8 qf[4];
#pragma unroll
        for (int kc = 0; kc < 4; ++kc)
            qf[kc] = *(const bf16x8*)&Qh[(size_t)(qw + r32) * HDIM + kc * 16 + half * 8];

        f32x16 ot[2] = {};                           // O^T: col=q, row=d (2 d-tiles)
        f32x16 lacc = {};                            // ones-MFMA denominator
        const int q = qw + r32;

        stage(0, 0);
#pragma unroll 1
        for (int it = 0; it < nk; ++it) {
            const int k0 = it * 128;
            const int buf = it & 1;
            __syncthreads();                         // buf's DMA landed; prior reads done
            if (it + 1 < nk) stage(buf ^ 1, k0 + 128);

            const bool diag = (it == nk - 1);
            // two 64-key half-passes: st[2] live (not st[4])
#pragma unroll
            for (int hp = 0; hp < 2; ++hp) {
                f32x16 st[2] = {};
#pragma unroll
                for (int tt = 0; tt < 2; ++tt) {
                    const int t = hp * 2 + tt;
#pragma unroll
                    for (int kc = 0; kc < 4; ++kc) {
                        bf16x8 kf = *(const bf16x8*)&Ks[buf][t * 32 + r32]
                                        [(kc * 16 + half * 8 + 8 * r32) & 63];
                        st[tt] = __builtin_amdgcn_mfma_f32_32x32x16_bf16(kf, qf[kc], st[tt], 0, 0, 0);
                    }
                }
                if (diag) {                          // diagonal-touching tile
#pragma unroll
                    for (int tt = 0; tt < 2; ++tt) {
                        const int t = hp * 2 + tt;
#pragma unroll
                        for (int r = 0; r < 16; ++r) {
                            const int key = k0 + t * 32 + (r & 3) + 8 * (r >> 2) + 4 * half;
                            if (key > q) st[tt][r] = -__builtin_inff();
                        }
                    }
                }
                // exp2 -> bf16 pairs -> permlane32_swap -> PV B-frags in-reg
#pragma unroll
                for (int tt = 0; tt < 2; ++tt) {
                    const int t = hp * 2 + tt;
                    unsigned int w[8];
#pragma unroll
                    for (int i = 0; i < 8; ++i) {
                        bf16x2 t2 = {(bf16)fast_exp2(st[tt][2 * i]),
                                     (bf16)fast_exp2(st[tt][2 * i + 1])};
                        w[i] = __builtin_bit_cast(unsigned int, t2);
                    }
                    // exchange halves: lane pair (l, l+32) share q; after swap each
                    // lane holds keys {base + half*8 + 0..7} in word order
                    asm volatile("v_permlane32_swap_b32 %0, %1" : "+v"(w[0]), "+v"(w[2]));
                    asm volatile("v_permlane32_swap_b32 %0, %1" : "+v"(w[1]), "+v"(w[3]));
                    asm volatile("v_permlane32_swap_b32 %0, %1" : "+v"(w[4]), "+v"(w[6]));
                    asm volatile("v_permlane32_swap_b32 %0, %1" : "+v"(w[5]), "+v"(w[7]));
#pragma unroll
                    for (int kcL = 0; kcL < 2; ++kcL) {
                        u32x4 wv = {w[4 * kcL + 0], w[4 * kcL + 1], w[4 * kcL + 2], w[4 * kcL + 3]};
                        bf16x8 pb = __builtin_bit_cast(bf16x8, wv);
                        lacc = __builtin_amdgcn_mfma_f32_32x32x16_bf16(ones, pb, lacc, 0, 0, 0);
#pragma unroll
                        for (int dt = 0; dt < 2; ++dt) {
                            bf16x8 vf = *(const bf16x8*)&Vs[buf][dt * 32 + r32]
                                            [(t * 32 + kcL * 16 + half * 8 + 8 * r32) & 127];
                            ot[dt] = __builtin_amdgcn_mfma_f32_32x32x16_bf16(vf, pb, ot[dt], 0, 0, 0);
                        }
                    }
                }
            }
        }
        __syncthreads();                             // reads done before next phase restages

        const float inv = 1.f / lacc[0];             // lacc rows all equal = sum_k P
        const int sq = qw + r32;
#pragma unroll
        for (int dt = 0; dt < 2; ++dt)
#pragma unroll
            for (int e = 0; e < 4; ++e) {
                bf16x4 pk = {(bf16)(ot[dt][4 * e + 0] * inv), (bf16)(ot[dt][4 * e + 1] * inv),
                             (bf16)(ot[dt][4 * e + 2] * inv), (bf16)(ot[dt][4 * e + 3] * inv)};
                *(bf16x4*)&O[((size_t)(b * SEQ + sq)) * EMBED + h * HDIM
                             + dt * 32 + half * 4 + 8 * e] = pk;
            }
    }
}

// ---------------------------------------------------------------------------
extern "C" void kernel_launch(void* const* d_in, const int* in_sizes, int n_in,
                              void* d_out, int out_size, void* d_ws, size_t ws_size,
                              hipStream_t stream) {
    const float* q_in = (const float*)d_in[0];
    const float* k_in = (const float*)d_in[1];
    const float* v_in = (const float*)d_in[2];
    // d_in[3] = causal mask — applied analytically
    const float* Wq = (const float*)d_in[4];
    const float* bq = (const float*)d_in[5];
    const float* Wk = (const float*)d_in[6];
    const float* bk = (const float*)d_in[7];
    const float* Wv = (const float*)d_in[8];
    const float* bv = (const float*)d_in[9];
    const float* Wo = (const float*)d_in[10];
    const float* bo = (const float*)d_in[11];

    bf16* ws = (bf16*)d_ws;
    // [0,12M): Xq,Xk,Xv  [12M,16M): Wq,Wk,Wv,Wo  [16M,28M): Qp,Kp,Vtp
    // AO aliases Xq (free after gemm_qkv).
    bf16* Xb  = ws;
    bf16* Wb  = ws + 3 * XSZ;
    bf16* Qp  = ws + 3 * XSZ + 4 * WSZ;
    bf16* Kp  = Qp + XSZ;
    bf16* Vtp = Kp + XSZ;
    bf16* AO  = ws;

    const size_t total = 3 * XSZ + 4 * WSZ;   // 16M elems
    dim3 bb(256);
    cvt_bf16<<<dim3((unsigned)(total / 8 / 256)), bb, 0, stream>>>(
        q_in, k_in, v_in, Wq, Wk, Wv, Wo, ws);
    gemm_qkv<<<dim3(MTOT / 128, EMBED / 64, 3), bb, 0, stream>>>(
        Xb, Xb + XSZ, Xb + 2 * XSZ, Wb, Wb + WSZ, Wb + 2 * WSZ,
        bq, bk, bv, Qp, Kp, Vtp);
    attn_flash<<<dim3(256), bb, 0, stream>>>(Qp, Kp, Vtp, AO);
    gemm_out<<<dim3(MTOT / 128, EMBED / 64), bb, 0, stream>>>(
        AO, Wb + 3 * WSZ, bo, (float*)d_out);
}

// Round 10
// 232.206 us; speedup vs baseline: 1.0172x; 1.0172x over previous
//
#include <hip/hip_runtime.h>
#include <hip/hip_bf16.h>

// Fused causal MHA. B=2, S=2048, E=1024, H=16, D=64. fp32 in/out.
// R19: GEMMs keep R17's proven geometry (qkv 128x128 dbuf 64KB; out
// 128x64 dbuf 48KB) but replace __syncthreads (which drains vmcnt(0))
// with raw s_barrier + COUNTED s_waitcnt vmcnt(N): tile t+1's loads stay
// in flight across the barrier; only tile t's must have landed.
// R18 lesson: occupancy 14->28.6% with dur WORSE (45.4->54.9) -> awake-
// wave supply was not the constraint; the per-iter vmcnt(0) drain is.
// Safety: one barrier/iter bounds skew; stage(t+1) overwrites the buffer
// last read at compute(t-1), complete before this barrier.
// R13: LDS staging IS the prefetch pipeline. R14: setprio null.
// R16: v_exp_f32 + split S^T live ranges verified good. attn unchanged.

typedef __bf16 bf16;
typedef bf16 bf16x2 __attribute__((ext_vector_type(2)));
typedef bf16 bf16x4 __attribute__((ext_vector_type(4)));
typedef bf16 bf16x8 __attribute__((ext_vector_type(8)));
typedef float f32x4 __attribute__((ext_vector_type(4)));
typedef float f32x16 __attribute__((ext_vector_type(16)));
typedef unsigned int u32x4 __attribute__((ext_vector_type(4)));

constexpr int BSZ = 2, SEQ = 2048, EMBED = 1024, HEADS = 16, HDIM = 64;
constexpr int MTOT = BSZ * SEQ;       // 4096
constexpr int KDIM = EMBED;           // 1024
constexpr float QSCALE = 0.125f * 1.4426950408889634f;  // 1/sqrt(64) * log2(e)

constexpr size_t XSZ = (size_t)MTOT * EMBED;   // 4M elems (1<<22)
constexpr size_t WSZ = (size_t)EMBED * EMBED;  // 1M elems (1<<20)

// async global->LDS, 16B/lane; lds dest wave-uniform base + lane*16
__device__ inline void load_lds16(const bf16* g, bf16* l) {
    __builtin_amdgcn_global_load_lds(
        (const __attribute__((address_space(1))) unsigned int*)g,
        (__attribute__((address_space(3))) unsigned int*)l, 16, 0, 0);
}

// bare v_exp_f32 (2^x); no libm special-case guards. -inf -> 0 in HW.
__device__ inline float fast_exp2(float x) {
    float r;
    asm("v_exp_f32 %0, %1" : "=v"(r) : "v"(x));
    return r;
}

// ---------------------------------------------------------------------------
// fp32 -> bf16 conversion: 3 X tensors (4M each) + 4 W tensors (1M each).
// ---------------------------------------------------------------------------
__global__ __launch_bounds__(256) void cvt_bf16(
    const float* __restrict__ x0, const float* __restrict__ x1, const float* __restrict__ x2,
    const float* __restrict__ w0, const float* __restrict__ w1,
    const float* __restrict__ w2, const float* __restrict__ w3,
    bf16* __restrict__ dst) {
    const size_t i = ((size_t)blockIdx.x * blockDim.x + threadIdx.x) * 8;
    const float* src;
    size_t off;
    if (i < 3 * XSZ) {
        const int s = (int)(i >> 22);
        src = s == 0 ? x0 : (s == 1 ? x1 : x2);
        off = i & (XSZ - 1);
    } else {
        const size_t j = i - 3 * XSZ;
        const int s = (int)(j >> 20);
        src = s == 0 ? w0 : (s == 1 ? w1 : (s == 2 ? w2 : w3));
        off = j & (WSZ - 1);
    }
    float4 a = *(const float4*)(src + off);
    float4 b = *(const float4*)(src + off + 4);
    bf16x8 v = {(bf16)a.x, (bf16)a.y, (bf16)a.z, (bf16)a.w,
                (bf16)b.x, (bf16)b.y, (bf16)b.z, (bf16)b.w};
    *(bf16x8*)(dst + i) = v;
}

// ---------------------------------------------------------------------------
// m97-style GEMM inner loop, R19: dbuf + raw barrier + counted vmcnt.
// Per iter: s_barrier; stage(t+1); vmcnt(8) [t's loads landed, t+1's in
// flight]; compute(t). Last iter: vmcnt(0) (t's loads had a full compute
// phase to land). XOR row-rotation swizzle unchanged (verified R8).
// ---------------------------------------------------------------------------
struct MMCtx {
    int wave, lane, quad, l16, wm, wn, lrow, lcol;
};
__device__ inline MMCtx mm_ctx() {
    MMCtx c;
    const int tid = threadIdx.x;
    c.wave = tid >> 6; c.lane = tid & 63;
    c.quad = c.lane >> 4; c.l16 = c.lane & 15;
    c.wm = (c.wave & 1) * 64; c.wn = (c.wave >> 1) * 64;
    c.lrow = c.lane >> 3; c.lcol = (c.lane & 7) * 8;
    return c;
}

template <bool SWAP>
__device__ inline void mm_loop(const bf16* __restrict__ A, const bf16* __restrict__ W,
                               int rowA0, int rowB0, const MMCtx& c,
                               bf16 (*As)[64], bf16 (*Bs)[64], f32x4 acc[4][4]) {
    auto stage = [&](int buf, int k0) {
#pragma unroll
        for (int i = 0; i < 4; ++i) {
            const int r0 = (c.wave * 4 + i) * 8;
            const int row = r0 + c.lrow;
            const int gcol = (c.lcol - 8 * row) & 63;
            load_lds16(&A[(size_t)(rowA0 + row) * KDIM + k0 + gcol], &As[buf * 128 + r0][0]);
            load_lds16(&W[(size_t)(rowB0 + row) * KDIM + k0 + gcol], &Bs[buf * 128 + r0][0]);
        }
    };
    stage(0, 0);
    int cur = 0;
#pragma unroll 1
    for (int k0 = 0; k0 < KDIM; k0 += 64) {
        __builtin_amdgcn_s_barrier();            // all waves done reading cur^1
        __builtin_amdgcn_sched_barrier(0);       // pin: stage stays below barrier
        if (k0 + 64 < KDIM) {
            stage(cur ^ 1, k0 + 64);             // 8 loads, stay in flight
            asm volatile("s_waitcnt vmcnt(8)" ::: "memory");   // tile t landed
        } else {
            asm volatile("s_waitcnt vmcnt(0)" ::: "memory");
        }
        __builtin_amdgcn_sched_barrier(0);       // pin: ds_reads stay below wait
        for (int ks = 0; ks < 64; ks += 32) {
            bf16x8 af[4], bfr[4];
            for (int mt = 0; mt < 4; ++mt) {
                const int row = c.wm + mt * 16 + c.l16;
                af[mt] = *(const bf16x8*)&As[cur * 128 + row][(ks + c.quad * 8 + 8 * row) & 63];
            }
            for (int nt = 0; nt < 4; ++nt) {
                const int row = c.wn + nt * 16 + c.l16;
                bfr[nt] = *(const bf16x8*)&Bs[cur * 128 + row][(ks + c.quad * 8 + 8 * row) & 63];
            }
            for (int mt = 0; mt < 4; ++mt)
                for (int nt = 0; nt < 4; ++nt)
                    acc[mt][nt] = SWAP
                        ? __builtin_amdgcn_mfma_f32_16x16x32_bf16(bfr[nt], af[mt], acc[mt][nt], 0, 0, 0)
                        : __builtin_amdgcn_mfma_f32_16x16x32_bf16(af[mt], bfr[nt], acc[mt][nt], 0, 0, 0);
        }
        cur ^= 1;
    }
}

// ---------------------------------------------------------------------------
// QKV projection (R17 geometry): 128x128 tiles, acc 4x4, dbuf 64KB -> 2/CU,
// grid (32,8,3)=768. z=0: Q scaled; z=1: K; z=2: V -> [B,H,D,S].
// ---------------------------------------------------------------------------
__global__ __launch_bounds__(256) void gemm_qkv(
    const bf16* __restrict__ Xq, const bf16* __restrict__ Xk, const bf16* __restrict__ Xv,
    const bf16* __restrict__ Wq, const bf16* __restrict__ Wk, const bf16* __restrict__ Wv,
    const float* __restrict__ bq, const float* __restrict__ bk, const float* __restrict__ bv,
    bf16* __restrict__ Qp, bf16* __restrict__ Kp, bf16* __restrict__ Vtp) {
    __shared__ bf16 As[256][64];   // 2 x 128 rows (double buffer)
    __shared__ bf16 Bs[256][64];

    const int z = blockIdx.z;
    const bf16* A     = z == 0 ? Xq : (z == 1 ? Xk : Xv);
    const bf16* W     = z == 0 ? Wq : (z == 1 ? Wk : Wv);
    const float* bias = z == 0 ? bq : (z == 1 ? bk : bv);
    const float scale = z == 0 ? QSCALE : 1.0f;

    const MMCtx c = mm_ctx();
    const int rowA0 = blockIdx.x * 128;
    const int rowB0 = blockIdx.y * 128;
    f32x4 acc[4][4] = {};

    if (z < 2) {
        mm_loop<true>(A, W, rowA0, rowB0, c, As, Bs, acc);
        bf16* dst = z == 0 ? Qp : Kp;
        for (int mt = 0; mt < 4; ++mt) {
            const int xrow = rowA0 + c.wm + mt * 16 + c.l16;
            const int b = xrow >> 11, s = xrow & (SEQ - 1);
            for (int nt = 0; nt < 4; ++nt) {
                const int f0 = rowB0 + c.wn + nt * 16 + c.quad * 4;
                const float4 bb = *(const float4*)&bias[f0];
                const int h = f0 >> 6, d0 = f0 & (HDIM - 1);
                f32x4 a = acc[mt][nt];
                bf16x4 pk = {(bf16)((a[0] + bb.x) * scale), (bf16)((a[1] + bb.y) * scale),
                             (bf16)((a[2] + bb.z) * scale), (bf16)((a[3] + bb.w) * scale)};
                *(bf16x4*)&dst[(((size_t)(b * HEADS + h)) * SEQ + s) * HDIM + d0] = pk;
            }
        }
    } else {
        mm_loop<false>(A, W, rowA0, rowB0, c, As, Bs, acc);
        for (int nt = 0; nt < 4; ++nt) {
            const int f = rowB0 + c.wn + nt * 16 + c.l16;
            const float bb = bias[f];
            const int h = f >> 6, d = f & (HDIM - 1);
            for (int mt = 0; mt < 4; ++mt) {
                const int xrow0 = rowA0 + c.wm + mt * 16 + c.quad * 4;
                const int b = xrow0 >> 11, s0 = xrow0 & (SEQ - 1);
                f32x4 a = acc[mt][nt];
                bf16x4 pk = {(bf16)(a[0] + bb), (bf16)(a[1] + bb),
                             (bf16)(a[2] + bb), (bf16)(a[3] + bb)};
                *(bf16x4*)&Vtp[(((size_t)(b * HEADS + h)) * HDIM + d) * SEQ + s0] = pk;
            }
        }
    }
}

// ---------------------------------------------------------------------------
// Output projection: 128x64 tiles -> grid (32,16) = 512 blocks.
// R19: dbuf + raw barrier + counted vmcnt(6). 48KB LDS -> 3/CU.
// ---------------------------------------------------------------------------
__global__ __launch_bounds__(256) void gemm_out(const bf16* __restrict__ A,
                                                const bf16* __restrict__ W,
                                                const float* __restrict__ bias,
                                                float* __restrict__ C) {
    __shared__ bf16 As[256][64];   // 2 x 128 rows
    __shared__ bf16 Bs[128][64];   // 2 x 64 rows

    const int tid = threadIdx.x;
    const int wave = tid >> 6, lane = tid & 63;
    const int quad = lane >> 4, l16 = lane & 15;
    const int wm = (wave & 1) * 64, wn = (wave >> 1) * 32;
    const int lrow = lane >> 3, lcol = (lane & 7) * 8;
    const int rowA0 = blockIdx.x * 128;   // M rows
    const int rowB0 = blockIdx.y * 64;    // N features

    auto stage = [&](int buf, int k0) {
#pragma unroll
        for (int i = 0; i < 4; ++i) {
            const int r0 = (wave * 4 + i) * 8;
            const int row = r0 + lrow;
            const int gcol = (lcol - 8 * row) & 63;
            load_lds16(&A[(size_t)(rowA0 + row) * KDIM + k0 + gcol], &As[buf * 128 + r0][0]);
        }
#pragma unroll
        for (int i = 0; i < 2; ++i) {
            const int r0 = (wave * 2 + i) * 8;
            const int row = r0 + lrow;
            const int gcol = (lcol - 8 * row) & 63;
            load_lds16(&W[(size_t)(rowB0 + row) * KDIM + k0 + gcol], &Bs[buf * 64 + r0][0]);
        }
    };

    f32x4 acc[4][2] = {};
    stage(0, 0);
    int cur = 0;
#pragma unroll 1
    for (int k0 = 0; k0 < KDIM; k0 += 64) {
        __builtin_amdgcn_s_barrier();
        __builtin_amdgcn_sched_barrier(0);
        if (k0 + 64 < KDIM) {
            stage(cur ^ 1, k0 + 64);
            asm volatile("s_waitcnt vmcnt(6)" ::: "memory");
        } else {
            asm volatile("s_waitcnt vmcnt(0)" ::: "memory");
        }
        __builtin_amdgcn_sched_barrier(0);
        for (int ks = 0; ks < 64; ks += 32) {
            bf16x8 af[4], bfr[2];
            for (int mt = 0; mt < 4; ++mt) {
                const int row = wm + mt * 16 + l16;
                af[mt] = *(const bf16x8*)&As[cur * 128 + row][(ks + quad * 8 + 8 * row) & 63];
            }
            for (int nt = 0; nt < 2; ++nt) {
                const int row = wn + nt * 16 + l16;
                bfr[nt] = *(const bf16x8*)&Bs[cur * 64 + row][(ks + quad * 8 + 8 * row) & 63];
            }
            for (int mt = 0; mt < 4; ++mt)
                for (int nt = 0; nt < 2; ++nt)
                    acc[mt][nt] = __builtin_amdgcn_mfma_f32_16x16x32_bf16(
                        bfr[nt], af[mt], acc[mt][nt], 0, 0, 0);   // SWAP orientation
        }
        cur ^= 1;
    }

    for (int mt = 0; mt < 4; ++mt) {
        const int row = rowA0 + wm + mt * 16 + l16;
        for (int nt = 0; nt < 2; ++nt) {
            const int f0 = rowB0 + wn + nt * 16 + quad * 4;
            const float4 bb = *(const float4*)&bias[f0];
            f32x4 a = acc[mt][nt];
            float4 v = {a[0] + bb.x, a[1] + bb.y, a[2] + bb.z, a[3] + bb.w};
            *(float4*)&C[(size_t)row * EMBED + f0] = v;
        }
    }
}

// ---------------------------------------------------------------------------
// Flash attention, causal. R16 (unchanged): 32x32x16 MFMA, in-register P,
// 256 blocks x 4 waves; block owns q-tiles {15-p, p} (128 rows each).
// Per 128-key iter per wave, two 64-key half-passes:
//   QK^T (8 MFMA) -> mask -> exp2 (v_exp_f32) -> pack+permlane -> PV (12
//   MFMA incl. ones-denominator); st[2] live instead of st[4].
// K/V double-buffered DMA staging (L2-resident; 4 heads per XCD). LDS 64KB.
// ---------------------------------------------------------------------------
__global__ __launch_bounds__(256, 1) void attn_flash(const bf16* __restrict__ Q,
                                                     const bf16* __restrict__ K,
                                                     const bf16* __restrict__ Vt,
                                                     bf16* __restrict__ O) {
    const int l = blockIdx.x;                    // 0..255
    const int a = l & 7, s = l >> 3;             // XCD, slot 0..31
    const int bh = 4 * a + (s >> 3);             // 4 heads per XCD
    const int p = s & 7;                         // 0..7
    const int wave = threadIdx.x >> 6, lane = threadIdx.x & 63;
    const int r32 = lane & 31, half = lane >> 5;

    const bf16* Qh = Q + (size_t)bh * SEQ * HDIM;
    const bf16* Kh = K + (size_t)bh * SEQ * HDIM;
    const bf16* Vh = Vt + (size_t)bh * HDIM * SEQ;

    __shared__ bf16 Ks[2][128][64];  // [buf][key][d], col rotated by 8*key mod 64
    __shared__ bf16 Vs[2][64][128];  // [buf][d][key], col rotated by 8*d mod 128

    const int b = bh >> 4, h = bh & 15;

    // stage one 128-key tile (K: 128x64, V: 64x128), 4 DMA passes each
    auto stage = [&](int buf, int k0) {
#pragma unroll
        for (int cc = 0; cc < 4; ++cc) {
            const int krow = cc * 32 + wave * 8 + (lane >> 3);        // 0..127
            const int kg = (((lane & 7) * 8) - 8 * krow) & 63;
            load_lds16(&Kh[(size_t)(k0 + krow) * HDIM + kg], &Ks[buf][cc * 32 + wave * 8][0]);
            const int vrow = cc * 16 + wave * 4 + (lane >> 4);        // 0..63
            const int vg = (((lane & 15) * 8) - 8 * vrow) & 127;
            load_lds16(&Vh[(size_t)vrow * SEQ + k0 + vg], &Vs[buf][cc * 16 + wave * 4][0]);
        }
    };

    bf16x8 ones;
#pragma unroll
    for (int i = 0; i < 8; ++i) ones[i] = (bf16)1.0f;

#pragma unroll 1
    for (int phase = 0; phase < 2; ++phase) {
        const int qt = phase == 0 ? (15 - p) : p;    // 128-row q-tile index
        const int qw = qt * 128 + wave * 32;         // this wave's 32 q-rows
        const int nk = qt + 1;                       // 128-key iterations

        // Q^T B-frags: lane supplies Q[qw+r32][kc*16 + half*8 + e]
        bf16x8 qf[4];
#pragma unroll
        for (int kc = 0; kc < 4; ++kc)
            qf[kc] = *(const bf16x8*)&Qh[(size_t)(qw + r32) * HDIM + kc * 16 + half * 8];

        f32x16 ot[2] = {};                           // O^T: col=q, row=d (2 d-tiles)
        f32x16 lacc = {};                            // ones-MFMA denominator
        const int q = qw + r32;

        stage(0, 0);
#pragma unroll 1
        for (int it = 0; it < nk; ++it) {
            const int k0 = it * 128;
            const int buf = it & 1;
            __syncthreads();                         // buf's DMA landed; prior reads done
            if (it + 1 < nk) stage(buf ^ 1, k0 + 128);

            const bool diag = (it == nk - 1);
            // two 64-key half-passes: st[2] live (not st[4])
#pragma unroll
            for (int hp = 0; hp < 2; ++hp) {
                f32x16 st[2] = {};
#pragma unroll
                for (int tt = 0; tt < 2; ++tt) {
                    const int t = hp * 2 + tt;
#pragma unroll
                    for (int kc = 0; kc < 4; ++kc) {
                        bf16x8 kf = *(const bf16x8*)&Ks[buf][t * 32 + r32]
                                        [(kc * 16 + half * 8 + 8 * r32) & 63];
                        st[tt] = __builtin_amdgcn_mfma_f32_32x32x16_bf16(kf, qf[kc], st[tt], 0, 0, 0);
                    }
                }
                if (diag) {                          // diagonal-touching tile
#pragma unroll
                    for (int tt = 0; tt < 2; ++tt) {
                        const int t = hp * 2 + tt;
#pragma unroll
                        for (int r = 0; r < 16; ++r) {
                            const int key = k0 + t * 32 + (r & 3) + 8 * (r >> 2) + 4 * half;
                            if (key > q) st[tt][r] = -__builtin_inff();
                        }
                    }
                }
                // exp2 -> bf16 pairs -> permlane32_swap -> PV B-frags in-reg
#pragma unroll
                for (int tt = 0; tt < 2; ++tt) {
                    const int t = hp * 2 + tt;
                    unsigned int w[8];
#pragma unroll
                    for (int i = 0; i < 8; ++i) {
                        bf16x2 t2 = {(bf16)fast_exp2(st[tt][2 * i]),
                                     (bf16)fast_exp2(st[tt][2 * i + 1])};
                        w[i] = __builtin_bit_cast(unsigned int, t2);
                    }
                    // exchange halves: lane pair (l, l+32) share q; after swap each
                    // lane holds keys {base + half*8 + 0..7} in word order
                    asm volatile("v_permlane32_swap_b32 %0, %1" : "+v"(w[0]), "+v"(w[2]));
                    asm volatile("v_permlane32_swap_b32 %0, %1" : "+v"(w[1]), "+v"(w[3]));
                    asm volatile("v_permlane32_swap_b32 %0, %1" : "+v"(w[4]), "+v"(w[6]));
                    asm volatile("v_permlane32_swap_b32 %0, %1" : "+v"(w[5]), "+v"(w[7]));
#pragma unroll
                    for (int kcL = 0; kcL < 2; ++kcL) {
                        u32x4 wv = {w[4 * kcL + 0], w[4 * kcL + 1], w[4 * kcL + 2], w[4 * kcL + 3]};
                        bf16x8 pb = __builtin_bit_cast(bf16x8, wv);
                        lacc = __builtin_amdgcn_mfma_f32_32x32x16_bf16(ones, pb, lacc, 0, 0, 0);
#pragma unroll
                        for (int dt = 0; dt < 2; ++dt) {
                            bf16x8 vf = *(const bf16x8*)&Vs[buf][dt * 32 + r32]
                                            [(t * 32 + kcL * 16 + half * 8 + 8 * r32) & 127];
                            ot[dt] = __builtin_amdgcn_mfma_f32_32x32x16_bf16(vf, pb, ot[dt], 0, 0, 0);
                        }
                    }
                }
            }
        }
        __syncthreads();                             // reads done before next phase restages

        const float inv = 1.f / lacc[0];             // lacc rows all equal = sum_k P
        const int sq = qw + r32;
#pragma unroll
        for (int dt = 0; dt < 2; ++dt)
#pragma unroll
            for (int e = 0; e < 4; ++e) {
                bf16x4 pk = {(bf16)(ot[dt][4 * e + 0] * inv), (bf16)(ot[dt][4 * e + 1] * inv),
                             (bf16)(ot[dt][4 * e + 2] * inv), (bf16)(ot[dt][4 * e + 3] * inv)};
                *(bf16x4*)&O[((size_t)(b * SEQ + sq)) * EMBED + h * HDIM
                             + dt * 32 + half * 4 + 8 * e] = pk;
            }
    }
}

// ---------------------------------------------------------------------------
extern "C" void kernel_launch(void* const* d_in, const int* in_sizes, int n_in,
                              void* d_out, int out_size, void* d_ws, size_t ws_size,
                              hipStream_t stream) {
    const float* q_in = (const float*)d_in[0];
    const float* k_in = (const float*)d_in[1];
    const float* v_in = (const float*)d_in[2];
    // d_in[3] = causal mask — applied analytically
    const float* Wq = (const float*)d_in[4];
    const float* bq = (const float*)d_in[5];
    const float* Wk = (const float*)d_in[6];
    const float* bk = (const float*)d_in[7];
    const float* Wv = (const float*)d_in[8];
    const float* bv = (const float*)d_in[9];
    const float* Wo = (const float*)d_in[10];
    const float* bo = (const float*)d_in[11];

    bf16* ws = (bf16*)d_ws;
    // [0,12M): Xq,Xk,Xv  [12M,16M): Wq,Wk,Wv,Wo  [16M,28M): Qp,Kp,Vtp
    // AO aliases Xq (free after gemm_qkv).
    bf16* Xb  = ws;
    bf16* Wb  = ws + 3 * XSZ;
    bf16* Qp  = ws + 3 * XSZ + 4 * WSZ;
    bf16* Kp  = Qp + XSZ;
    bf16* Vtp = Kp + XSZ;
    bf16* AO  = ws;

    const size_t total = 3 * XSZ + 4 * WSZ;   // 16M elems
    dim3 bb(256);
    cvt_bf16<<<dim3((unsigned)(total / 8 / 256)), bb, 0, stream>>>(
        q_in, k_in, v_in, Wq, Wk, Wv, Wo, ws);
    gemm_qkv<<<dim3(MTOT / 128, EMBED / 128, 3), bb, 0, stream>>>(
        Xb, Xb + XSZ, Xb + 2 * XSZ, Wb, Wb + WSZ, Wb + 2 * WSZ,
        bq, bk, bv, Qp, Kp, Vtp);
    attn_flash<<<dim3(256), bb, 0, stream>>>(Qp, Kp, Vtp, AO);
    gemm_out<<<dim3(MTOT / 128, EMBED / 64), bb, 0, stream>>>(
        AO, Wb + 3 * WSZ, bo, (float*)d_out);
}